// Round 4
// baseline (211.344 us; speedup 1.0000x reference)
//
#include <hip/hip_runtime.h>
#include <math.h>

#define DF 8192
#define NT 512

// XOR swizzle on float2 index, bits 1..3 (keeps float4 pairs adjacent+ordered)
#define PH(i) ((i) ^ (((i) >> 5) & 14))

__device__ __forceinline__ float2 cmul(float2 a, float2 b) {
    return make_float2(a.x * b.x - a.y * b.y, a.x * b.y + a.y * b.x);
}
__device__ __forceinline__ float2 cadd(float2 a, float2 b) { return make_float2(a.x + b.x, a.y + b.y); }
__device__ __forceinline__ float2 csub(float2 a, float2 b) { return make_float2(a.x - b.x, a.y - b.y); }
__device__ __forceinline__ float2 cmuli(float2 a) { return make_float2(-a.y, a.x); }   // a * i

#define RT_C 0.92387953251128674f
#define RT_S 0.38268343236508977f
#define RT_H 0.70710678118654752f

__device__ __forceinline__ float2 rootF(int j) {   // exp(-i*pi*j/8)
    switch (j & 7) {
        case 0:  return make_float2( 1.f,   0.f  );
        case 1:  return make_float2( RT_C, -RT_S );
        case 2:  return make_float2( RT_H, -RT_H );
        case 3:  return make_float2( RT_S, -RT_C );
        case 4:  return make_float2( 0.f,  -1.f  );
        case 5:  return make_float2(-RT_S, -RT_C );
        case 6:  return make_float2(-RT_H, -RT_H );
        default: return make_float2(-RT_C, -RT_S );
    }
}
__device__ __forceinline__ float2 rootI(int j) {   // exp(+i*pi*j/8)
    float2 r = rootF(j);
    return make_float2(r.x, -r.y);
}

__device__ __forceinline__ int brev9(int x) { return (int)(__brev((unsigned)x) >> 23); }

// ---- dual-row butterflies: one twiddle, two data streams (ILP-2) ----
__device__ __forceinline__ void bf_dif_dual(float2& a0, float2& b0, float2& a1, float2& b1, float2 W) {
    float2 d0 = csub(a0, b0); a0 = cadd(a0, b0); b0 = cmul(d0, W);
    float2 d1 = csub(a1, b1); a1 = cadd(a1, b1); b1 = cmul(d1, W);
}
__device__ __forceinline__ void bf_dit_dual(float2& a0, float2& b0, float2& a1, float2& b1, float2 W) {
    float2 w0 = cmul(b0, W); b0 = csub(a0, w0); a0 = cadd(a0, w0);
    float2 w1 = cmul(b1, W); b1 = csub(a1, w1); a1 = cadd(a1, w1);
}
__device__ __forceinline__ void bf_dit1_dual(float2& a0, float2& b0, float2& a1, float2& b1) {
    float2 t0 = b0; b0 = csub(a0, t0); a0 = cadd(a0, t0);
    float2 t1 = b1; b1 = csub(a1, t1); a1 = cadd(a1, t1);
}
__device__ __forceinline__ void bf_diti_dual(float2& a0, float2& b0, float2& a1, float2& b1) {
    float2 w0 = cmuli(b0); b0 = csub(a0, w0); a0 = cadd(a0, w0);
    float2 w1 = cmuli(b1); b1 = csub(a1, w1); a1 = cadd(a1, w1);
}

// 4 radix-2 DIF stages on 16 register elements, both rows, base twiddle wb.
__device__ __forceinline__ void fft16_dif_dual(float2 va[16], float2 vb[16], float2 wb) {
    const float2 wb2 = cmul(wb, wb);
    const float2 wb4 = cmul(wb2, wb2);
    const float2 wb8 = cmul(wb4, wb4);
    #pragma unroll
    for (int m = 0; m < 8; ++m) {
        float2 W = cmul(wb, rootF(m));
        bf_dif_dual(va[m], va[m + 8], vb[m], vb[m + 8], W);
    }
    #pragma unroll
    for (int m = 0; m < 4; ++m) {
        float2 W = cmul(wb2, rootF(2 * m));
        bf_dif_dual(va[m],     va[m + 4],  vb[m],     vb[m + 4],  W);
        bf_dif_dual(va[8 + m], va[12 + m], vb[8 + m], vb[12 + m], W);
    }
    #pragma unroll
    for (int m = 0; m < 2; ++m) {
        float2 W = cmul(wb4, rootF(4 * m));
        #pragma unroll
        for (int g = 0; g < 4; ++g) {
            int i = 4 * g + m;
            bf_dif_dual(va[i], va[i + 2], vb[i], vb[i + 2], W);
        }
    }
    #pragma unroll
    for (int g = 0; g < 8; ++g)
        bf_dif_dual(va[2 * g], va[2 * g + 1], vb[2 * g], vb[2 * g + 1], wb8);
}

// 3 radix-2 DIT stages on 8 register elements, both rows; wq = exp(+i*pi*lo/(4*hmin)).
__device__ __forceinline__ void fft8_dit_dual(float2 va[8], float2 vb[8], float2 wq) {
    const float2 wq2 = cmul(wq, wq);
    const float2 wq4 = cmul(wq2, wq2);
    #pragma unroll
    for (int g = 0; g < 4; ++g) bf_dit_dual(va[2 * g], va[2 * g + 1], vb[2 * g], vb[2 * g + 1], wq4);
    const float2 iwq2 = cmuli(wq2);
    #pragma unroll
    for (int g = 0; g < 2; ++g) {
        bf_dit_dual(va[4 * g],     va[4 * g + 2], vb[4 * g],     vb[4 * g + 2], wq2);
        bf_dit_dual(va[4 * g + 1], va[4 * g + 3], vb[4 * g + 1], vb[4 * g + 3], iwq2);
    }
    bf_dit_dual(va[0], va[4], vb[0], vb[4], wq);
    bf_dit_dual(va[1], va[5], vb[1], vb[5], cmul(wq, make_float2(RT_H, RT_H)));
    bf_dit_dual(va[2], va[6], vb[2], vb[6], cmuli(wq));
    bf_dit_dual(va[3], va[7], vb[3], vb[7], cmul(wq, make_float2(-RT_H, RT_H)));
}
__device__ __forceinline__ void fft8_dit1_dual(float2 va[8], float2 vb[8]) {
    #pragma unroll
    for (int g = 0; g < 4; ++g) bf_dit1_dual(va[2 * g], va[2 * g + 1], vb[2 * g], vb[2 * g + 1]);
    #pragma unroll
    for (int g = 0; g < 2; ++g) {
        bf_dit1_dual(va[4 * g],     va[4 * g + 2], vb[4 * g],     vb[4 * g + 2]);
        bf_diti_dual(va[4 * g + 1], va[4 * g + 3], vb[4 * g + 1], vb[4 * g + 3]);
    }
    bf_dit1_dual(va[0], va[4], vb[0], vb[4]);
    bf_dit_dual (va[1], va[5], vb[1], vb[5], make_float2(RT_H, RT_H));
    bf_diti_dual(va[2], va[6], vb[2], vb[6]);
    bf_dit_dual (va[3], va[7], vb[3], vb[7], make_float2(-RT_H, RT_H));
}

// Hermitian product + half-size-IFFT input prep for one (kappa, kappa+4096) pair.
// (A,B) = own pair post-stage13; (PA,PB) = partner pair post-stage13.
__device__ __forceinline__ float2 mega_combine(float2 A, float2 B, float2 PA, float2 PB,
                                               float2 W, float invN) {
    // P1 = X[k]Y[k]/N at k=kappa (X=(A+conj PB)/2, Y=-i(A-conj PB)/2)
    float X1r = 0.5f * (A.x + PB.x), X1i = 0.5f * (A.y - PB.y);
    float Y1r = 0.5f * (A.y + PB.y), Y1i = 0.5f * (PB.x - A.x);
    float2 P1 = make_float2((X1r * Y1r - X1i * Y1i) * invN, (X1r * Y1i + X1i * Y1r) * invN);
    // P2 at k=kappa+4096 (X=(B+conj PA)/2, Y=-i(B-conj PA)/2)
    float X2r = 0.5f * (B.x + PA.x), X2i = 0.5f * (B.y - PA.y);
    float Y2r = 0.5f * (B.y + PA.y), Y2i = 0.5f * (PA.x - B.x);
    float2 P2 = make_float2((X2r * Y2r - X2i * Y2i) * invN, (X2r * Y2i + X2i * Y2r) * invN);
    // U = (P1+P2) + i*(P1-P2)*W
    float2 S = cadd(P1, P2);
    float2 D = csub(P1, P2);
    float2 Dw = cmul(D, W);
    return make_float2(S.x - Dw.y, S.y + Dw.x);
}

__global__ __launch_bounds__(NT, 2)
void mcb4(const float* __restrict__ x, const float* __restrict__ y,
          const float* __restrict__ s1, const float* __restrict__ s2,
          const float* __restrict__ gamma, const float* __restrict__ beta,
          const int* __restrict__ h1, const int* __restrict__ h2,
          float* __restrict__ out)
{
    __shared__ float2 z[2 * DF];   // 128 KB: two rows
    float2* z0 = z;
    float2* z1 = z + DF;
    const int t = threadIdx.x;
    const int rA = blockIdx.x * 2, rB = rA + 1;

    // ---- zero both rows (b128) ----
    {
        float4* z4 = (float4*)z;
        #pragma unroll
        for (int m = 0; m < 16; ++m) z4[t + NT * m] = make_float4(0.f, 0.f, 0.f, 0.f);
    }
    __syncthreads();

    // ---- count sketches: x*s1 -> .x, y*s2 -> .y (h/s loads + PH shared) ----
    {
        float4 sv = ((const float4*)s1)[t];
        int4   hv = ((const int4*)h1)[t];
        float4 xa = ((const float4*)(x + (size_t)rA * 2048))[t];
        float4 xb = ((const float4*)(x + (size_t)rB * 2048))[t];
        int p0 = PH(hv.x), p1 = PH(hv.y), p2 = PH(hv.z), p3 = PH(hv.w);
        atomicAdd(&z0[p0].x, xa.x * sv.x);  atomicAdd(&z1[p0].x, xb.x * sv.x);
        atomicAdd(&z0[p1].x, xa.y * sv.y);  atomicAdd(&z1[p1].x, xb.y * sv.y);
        atomicAdd(&z0[p2].x, xa.z * sv.z);  atomicAdd(&z1[p2].x, xb.z * sv.z);
        atomicAdd(&z0[p3].x, xa.w * sv.w);  atomicAdd(&z1[p3].x, xb.w * sv.w);
        float2 tv = ((const float2*)s2)[t];
        int2   hw = ((const int2*)h2)[t];
        float2 ya = ((const float2*)(y + (size_t)rA * 1024))[t];
        float2 yb = ((const float2*)(y + (size_t)rB * 1024))[t];
        int q0 = PH(hw.x), q1 = PH(hw.y);
        atomicAdd(&z0[q0].y, ya.x * tv.x);  atomicAdd(&z1[q0].y, yb.x * tv.x);
        atomicAdd(&z0[q1].y, ya.y * tv.y);  atomicAdd(&z1[q1].y, yb.y * tv.y);
    }
    __syncthreads();

    float sn, cs;
    {
        float2 va[16], vb[16];

        // ---------- forward G1: h=4096..512, idx = t + 512m ----------
        #pragma unroll
        for (int m = 0; m < 16; ++m) { int p = PH(t + 512 * m); va[m] = z0[p]; vb[m] = z1[p]; }
        __sincosf(-(float)M_PI / 4096.f * (float)t, &sn, &cs);
        fft16_dif_dual(va, vb, make_float2(cs, sn));
        #pragma unroll
        for (int m = 0; m < 16; ++m) { int p = PH(t + 512 * m); z0[p] = va[m]; z1[p] = vb[m]; }
        __syncthreads();

        // ---------- forward G2: h=256..32, idx = lo + 32m + 512hi ----------
        {
            const int lo = t & 31, hi = t >> 5;
            #pragma unroll
            for (int m = 0; m < 16; ++m) { int p = PH(lo + 32 * m + 512 * hi); va[m] = z0[p]; vb[m] = z1[p]; }
            __sincosf(-(float)M_PI / 256.f * (float)lo, &sn, &cs);
            fft16_dif_dual(va, vb, make_float2(cs, sn));
            #pragma unroll
            for (int m = 0; m < 16; ++m) { int p = PH(lo + 32 * m + 512 * hi); z0[p] = va[m]; z1[p] = vb[m]; }
        }
        __syncthreads();

        // ---------- forward G3: h=16..2, idx = lo + 2m + 32hi ----------
        {
            const int lo = t & 1, hi = t >> 1;
            #pragma unroll
            for (int m = 0; m < 16; ++m) { int p = PH(lo + 2 * m + 32 * hi); va[m] = z0[p]; vb[m] = z1[p]; }
            __sincosf(-(float)M_PI / 16.f * (float)lo, &sn, &cs);
            fft16_dif_dual(va, vb, make_float2(cs, sn));
            #pragma unroll
            for (int m = 0; m < 16; ++m) { int p = PH(lo + 2 * m + 32 * hi); z0[p] = va[m]; z1[p] = vb[m]; }
        }
        __syncthreads();
    }

    // ---------- MEGA: stage13 + Hermitian product + U-prep + inverse h=1,2,4 ----------
    // Pre-stage13 pairs (2j,2j+1), j=8t+m. Post-stage13: even=Z[kappa], odd=Z[kappa+4096],
    // kappa = 512*brev3(m)+R, R=brev9(t). Partner pair at jp = 8*tp + (7-m), tp=brev9(512-R);
    // t==0 (R==0): partner = own pair TBL[m], with a/b swap at m==0.
    float2 uA[8], uB[8];
    {
        const int R  = brev9(t);
        const int tp = brev9((512 - R) & 511);
        __sincosf((float)M_PI / 4096.f * (float)R, &sn, &cs);
        const float2 wR = make_float2(cs, sn);    // exp(+i*pi*R/4096)
        const float invN = 1.f / 8192.f;
        const int MB[8]   = {0, 4, 2, 6, 1, 5, 3, 7};       // brev3(m)
        const int TBL2[8] = {0, 2, 6, 4, 14, 12, 10, 8};    // 2*tbl[m] for t==0
        #pragma unroll
        for (int m = 0; m < 8; ++m) {
            int own = PH(16 * t + 2 * m);
            int pp  = (t == 0) ? PH(TBL2[m]) : PH(16 * tp + 2 * (7 - m));
            float4 qa = *(const float4*)&z0[own];
            float4 qb = *(const float4*)&z1[own];
            float4 ra = *(const float4*)&z0[pp];
            float4 rb = *(const float4*)&z1[pp];
            // stage-13 butterflies (W=1), own + partner, both rows
            float2 A0  = make_float2(qa.x + qa.z, qa.y + qa.w);
            float2 B0  = make_float2(qa.x - qa.z, qa.y - qa.w);
            float2 A1  = make_float2(qb.x + qb.z, qb.y + qb.w);
            float2 B1  = make_float2(qb.x - qb.z, qb.y - qb.w);
            float2 PA0 = make_float2(ra.x + ra.z, ra.y + ra.w);
            float2 PB0 = make_float2(ra.x - ra.z, ra.y - ra.w);
            float2 PA1 = make_float2(rb.x + rb.z, rb.y + rb.w);
            float2 PB1 = make_float2(rb.x - rb.z, rb.y - rb.w);
            if (m == 0) {
                if (t == 0) {   // kappa=0 self-pair: partner = own pair swapped
                    float2 s0 = PA0; PA0 = PB0; PB0 = s0;
                    float2 s1_ = PA1; PA1 = PB1; PB1 = s1_;
                }
            }
            float2 W = cmul(wR, rootI(MB[m]));
            uA[m] = mega_combine(A0, B0, PA0, PB0, W, invN);
            uB[m] = mega_combine(A1, B1, PA1, PB1, W, invN);
        }
        fft8_dit1_dual(uA, uB);   // inverse stages h=1,2,4
    }
    __syncthreads();              // all pair/partner reads complete before overwrite
    #pragma unroll
    for (int g = 0; g < 4; ++g) {
        int p = PH(8 * t + 2 * g);
        *(float4*)&z0[p] = make_float4(uA[2 * g].x, uA[2 * g].y, uA[2 * g + 1].x, uA[2 * g + 1].y);
        *(float4*)&z1[p] = make_float4(uB[2 * g].x, uB[2 * g].y, uB[2 * g + 1].x, uB[2 * g + 1].y);
    }
    __syncthreads();

    // ---------- inverse S2: h=8,16,32, idx = lo + 8m + 64hi ----------
    {
        const int lo = t & 7, hi = t >> 3;
        #pragma unroll
        for (int m = 0; m < 8; ++m) { int p = PH(lo + 8 * m + 64 * hi); uA[m] = z0[p]; uB[m] = z1[p]; }
        __sincosf((float)M_PI / 32.f * (float)lo, &sn, &cs);
        fft8_dit_dual(uA, uB, make_float2(cs, sn));
        #pragma unroll
        for (int m = 0; m < 8; ++m) { int p = PH(lo + 8 * m + 64 * hi); z0[p] = uA[m]; z1[p] = uB[m]; }
    }
    __syncthreads();

    // ---------- inverse S3: h=64,128,256, idx = lo + 64m + 512hi ----------
    {
        const int lo = t & 63, hi = t >> 6;
        #pragma unroll
        for (int m = 0; m < 8; ++m) { int p = PH(lo + 64 * m + 512 * hi); uA[m] = z0[p]; uB[m] = z1[p]; }
        __sincosf((float)M_PI / 256.f * (float)lo, &sn, &cs);
        fft8_dit_dual(uA, uB, make_float2(cs, sn));
        #pragma unroll
        for (int m = 0; m < 8; ++m) { int p = PH(lo + 64 * m + 512 * hi); z0[p] = uA[m]; z1[p] = uB[m]; }
    }
    __syncthreads();

    // ---------- inverse S4: h=512,1024,2048, idx = t + 512m; LN + L2 from regs ----------
    #pragma unroll
    for (int m = 0; m < 8; ++m) { int p = PH(t + 512 * m); uA[m] = z0[p]; uB[m] = z1[p]; }
    __sincosf((float)M_PI / 2048.f * (float)t, &sn, &cs);
    fft8_dit_dual(uA, uB, make_float2(cs, sn));
    // uA[m] = u[t+512m]: fusedA[2i] = .x, fusedA[2i+1] = .y (same for B)

    float lsA = 0.f, lqA = 0.f, lsB = 0.f, lqB = 0.f;
    #pragma unroll
    for (int m = 0; m < 8; ++m) {
        lsA += uA[m].x + uA[m].y;  lqA += uA[m].x * uA[m].x + uA[m].y * uA[m].y;
        lsB += uB[m].x + uB[m].y;  lqB += uB[m].x * uB[m].x + uB[m].y * uB[m].y;
    }
    #pragma unroll
    for (int k = 32; k >= 1; k >>= 1) {
        lsA += __shfl_xor(lsA, k);  lqA += __shfl_xor(lqA, k);
        lsB += __shfl_xor(lsB, k);  lqB += __shfl_xor(lqB, k);
    }
    const int wid = t >> 6, lane = t & 63;
    __syncthreads();                       // S4 reads complete before stash reuse
    if (lane == 0) { z0[wid] = make_float2(lsA, lqA); z1[wid] = make_float2(lsB, lqB); }
    __syncthreads();
    float tsA = 0.f, tqA = 0.f, tsB = 0.f, tqB = 0.f;
    #pragma unroll
    for (int w = 0; w < 8; ++w) {
        tsA += z0[w].x; tqA += z0[w].y;
        tsB += z1[w].x; tqB += z1[w].y;
    }
    const float muA = tsA * (1.f / (float)DF);
    const float muB = tsB * (1.f / (float)DF);
    const float rstdA = rsqrtf(tqA * (1.f / (float)DF) - muA * muA + 1e-5f);
    const float rstdB = rsqrtf(tqB * (1.f / (float)DF) - muB * muB + 1e-5f);

    const float2* g2  = (const float2*)gamma;
    const float2* bt2 = (const float2*)beta;
    float l2A = 0.f, l2B = 0.f;
    #pragma unroll
    for (int m = 0; m < 8; ++m) {
        int i = t + 512 * m;
        float2 g = g2[i], bb = bt2[i];
        float aE = (uA[m].x - muA) * rstdA * g.x + bb.x;
        float aO = (uA[m].y - muA) * rstdA * g.y + bb.y;
        float bE = (uB[m].x - muB) * rstdB * g.x + bb.x;
        float bO = (uB[m].y - muB) * rstdB * g.y + bb.y;
        uA[m] = make_float2(aE, aO);
        uB[m] = make_float2(bE, bO);
        l2A += aE * aE + aO * aO;
        l2B += bE * bE + bO * bO;
    }
    #pragma unroll
    for (int k = 32; k >= 1; k >>= 1) { l2A += __shfl_xor(l2A, k); l2B += __shfl_xor(l2B, k); }
    if (lane == 0) z0[8 + wid] = make_float2(l2A, l2B);
    __syncthreads();
    float t2A = 0.f, t2B = 0.f;
    #pragma unroll
    for (int w = 0; w < 8; ++w) { t2A += z0[8 + w].x; t2B += z0[8 + w].y; }
    const float invA = 1.f / fmaxf(sqrtf(t2A), 1e-12f);
    const float invB = 1.f / fmaxf(sqrtf(t2B), 1e-12f);

    float2* oA = (float2*)(out + (size_t)rA * DF);
    float2* oB = (float2*)(out + (size_t)rB * DF);
    #pragma unroll
    for (int m = 0; m < 8; ++m) {
        oA[t + 512 * m] = make_float2(uA[m].x * invA, uA[m].y * invA);
        oB[t + 512 * m] = make_float2(uB[m].x * invB, uB[m].y * invB);
    }
}

extern "C" void kernel_launch(void* const* d_in, const int* in_sizes, int n_in,
                              void* d_out, int out_size, void* d_ws, size_t ws_size,
                              hipStream_t stream) {
    const float* x     = (const float*)d_in[0];
    const float* y     = (const float*)d_in[1];
    const float* s1    = (const float*)d_in[2];
    const float* s2    = (const float*)d_in[3];
    const float* gamma = (const float*)d_in[4];
    const float* beta  = (const float*)d_in[5];
    const int*   h1    = (const int*)d_in[6];
    const int*   h2    = (const int*)d_in[7];
    float* out = (float*)d_out;

    hipLaunchKernelGGL(mcb4, dim3(2048), dim3(NT), 0, stream,
                       x, y, s1, s2, gamma, beta, h1, h2, out);
}

// Round 5
// 190.894 us; speedup vs baseline: 1.1071x; 1.1071x over previous
//
#include <hip/hip_runtime.h>
#include <math.h>

#define DF 8192
#define NT 1024

// XOR swizzle on float2 slot index: bits 2-4 ^= bits 4-6.
// Preserves bits 0-1 so b128 groups (4 consecutive slots, 4-aligned) stay contiguous.
// Kills the 16-way conflict of small-stride sweeps (lanes differing only in high bits).
#define SW(i) ((i) ^ ((((i) >> 4) & 7) << 2))

__device__ __forceinline__ float2 cmul(float2 a, float2 b) {
    return make_float2(a.x * b.x - a.y * b.y, a.x * b.y + a.y * b.x);
}
__device__ __forceinline__ float2 cadd(float2 a, float2 b) { return make_float2(a.x + b.x, a.y + b.y); }
__device__ __forceinline__ float2 csub(float2 a, float2 b) { return make_float2(a.x - b.x, a.y - b.y); }
__device__ __forceinline__ float2 cmuli(float2 a)  { return make_float2(-a.y, a.x); }   // a * +i
__device__ __forceinline__ float2 cmulmi(float2 a) { return make_float2(a.y, -a.x); }   // a * -i

#define RT_H 0.70710678118654752f

__device__ __forceinline__ int brev10(int x) { return (int)(__brev((unsigned)x) >> 22); }

__device__ __forceinline__ void bf_dif(float2& a, float2& b, float2 W) {
    float2 d = csub(a, b);
    a = cadd(a, b);
    b = cmul(d, W);
}
__device__ __forceinline__ void bf_dit(float2& a, float2& b, float2 W) {
    float2 bw = cmul(b, W);
    float2 ta = a;
    a = cadd(ta, bw);
    b = csub(ta, bw);
}
__device__ __forceinline__ void bf_dit1(float2& a, float2& b) {
    float2 tb = b, ta = a;
    a = cadd(ta, tb);
    b = csub(ta, tb);
}
__device__ __forceinline__ void bf_diti(float2& a, float2& b) {
    float2 bw = cmuli(b);
    float2 ta = a;
    a = cadd(ta, bw);
    b = csub(ta, bw);
}

// 3 radix-2 DIF stages on 8 register elements; w = exp(-i*pi*lo/(4s)), stride s.
__device__ __forceinline__ void fft8_dif(float2 v[8], float2 w) {
    const float2 w2 = cmul(w, w);
    const float2 w4 = cmul(w2, w2);
    bf_dif(v[0], v[4], w);
    bf_dif(v[1], v[5], cmul(w, make_float2(RT_H, -RT_H)));
    bf_dif(v[2], v[6], cmulmi(w));
    bf_dif(v[3], v[7], cmul(w, make_float2(-RT_H, -RT_H)));
    bf_dif(v[0], v[2], w2);
    bf_dif(v[1], v[3], cmulmi(w2));
    bf_dif(v[4], v[6], w2);
    bf_dif(v[5], v[7], cmulmi(w2));
    bf_dif(v[0], v[1], w4);
    bf_dif(v[2], v[3], w4);
    bf_dif(v[4], v[5], w4);
    bf_dif(v[6], v[7], w4);
}

// 2 radix-2 DIT stages on 4 register elements; q = exp(+i*pi*lo/(2s)), stride s.
__device__ __forceinline__ void fft4_dit(float2 v[4], float2 q) {
    const float2 q2 = cmul(q, q);
    bf_dit(v[0], v[1], q2);
    bf_dit(v[2], v[3], q2);
    bf_dit(v[0], v[2], q);
    bf_dit(v[1], v[3], cmuli(q));
}

// Hermitian product + half-size-IFFT input prep for one (kappa, kappa+4096) pair.
__device__ __forceinline__ float2 mega_combine(float2 A, float2 B, float2 PA, float2 PB,
                                               float2 W, float invN) {
    float X1r = 0.5f * (A.x + PB.x), X1i = 0.5f * (A.y - PB.y);
    float Y1r = 0.5f * (A.y + PB.y), Y1i = 0.5f * (PB.x - A.x);
    float2 P1 = make_float2((X1r * Y1r - X1i * Y1i) * invN, (X1r * Y1i + X1i * Y1r) * invN);
    float X2r = 0.5f * (B.x + PA.x), X2i = 0.5f * (B.y - PA.y);
    float Y2r = 0.5f * (B.y + PA.y), Y2i = 0.5f * (PA.x - B.x);
    float2 P2 = make_float2((X2r * Y2r - X2i * Y2i) * invN, (X2r * Y2i + X2i * Y2r) * invN);
    float2 S = cadd(P1, P2);
    float2 D = csub(P1, P2);
    float2 Dw = cmul(D, W);
    return make_float2(S.x - Dw.y, S.y + Dw.x);
}

__global__ __launch_bounds__(NT, 8)
void mcb5(const float* __restrict__ x, const float* __restrict__ y,
          const float* __restrict__ s1, const float* __restrict__ s2,
          const float* __restrict__ gamma, const float* __restrict__ beta,
          const int* __restrict__ h1, const int* __restrict__ h2,
          float* __restrict__ out)
{
    __shared__ float2 z[DF];   // 64 KB
    const int t = threadIdx.x;
    const int row = blockIdx.x;

    // ---- zero (b128 over raw slots; SW is a bijection) ----
    {
        float4* z4 = (float4*)z;
        #pragma unroll
        for (int m = 0; m < 4; ++m) z4[t + NT * m] = make_float4(0.f, 0.f, 0.f, 0.f);
    }
    __syncthreads();

    // ---- count sketches: x*s1 -> .x, y*s2 -> .y ----
    {
        float2 xv = ((const float2*)(x + (size_t)row * 2048))[t];
        float2 sv = ((const float2*)s1)[t];
        int2   hv = ((const int2*)h1)[t];
        atomicAdd(&z[SW(hv.x)].x, xv.x * sv.x);
        atomicAdd(&z[SW(hv.y)].x, xv.y * sv.y);
        float yv = (y + (size_t)row * 1024)[t];
        atomicAdd(&z[SW(h2[t])].y, yv * s2[t]);
    }
    __syncthreads();

    float sn, cs;

    // ---------- F1: h=4096,2048,1024; idx = t + 1024m ----------
    {
        float2 v[8];
        #pragma unroll
        for (int m = 0; m < 8; ++m) v[m] = z[SW(t + 1024 * m)];
        __sincosf(-(float)M_PI / 4096.f * (float)t, &sn, &cs);
        fft8_dif(v, make_float2(cs, sn));
        #pragma unroll
        for (int m = 0; m < 8; ++m) z[SW(t + 1024 * m)] = v[m];
    }
    __syncthreads();

    // ---------- F2: h=512,256,128; idx = lo + 128m + 1024hi ----------
    {
        const int lo = t & 127, hi = t >> 7;
        float2 v[8];
        #pragma unroll
        for (int m = 0; m < 8; ++m) v[m] = z[SW(lo + 128 * m + 1024 * hi)];
        __sincosf(-(float)M_PI / 512.f * (float)lo, &sn, &cs);
        fft8_dif(v, make_float2(cs, sn));
        #pragma unroll
        for (int m = 0; m < 8; ++m) z[SW(lo + 128 * m + 1024 * hi)] = v[m];
    }
    __syncthreads();

    // ---------- F3: h=64,32,16; idx = lo + 16m + 128hi ----------
    {
        const int lo = t & 15, hi = t >> 4;
        float2 v[8];
        #pragma unroll
        for (int m = 0; m < 8; ++m) v[m] = z[SW(lo + 16 * m + 128 * hi)];
        __sincosf(-(float)M_PI / 64.f * (float)lo, &sn, &cs);
        fft8_dif(v, make_float2(cs, sn));
        #pragma unroll
        for (int m = 0; m < 8; ++m) z[SW(lo + 16 * m + 128 * hi)] = v[m];
    }
    __syncthreads();

    // ---------- F4: h=8,4,2; idx = lo + 2m + 16hi ----------
    {
        const int lo = t & 1, hi = t >> 1;
        float2 v[8];
        #pragma unroll
        for (int m = 0; m < 8; ++m) v[m] = z[SW(lo + 2 * m + 16 * hi)];
        __sincosf(-(float)M_PI / 8.f * (float)lo, &sn, &cs);
        fft8_dif(v, make_float2(cs, sn));
        #pragma unroll
        for (int m = 0; m < 8; ++m) z[SW(lo + 2 * m + 16 * hi)] = v[m];
    }
    __syncthreads();

    // ---------- MEGA: stage13 + Hermitian product + U-prep + inverse h=1,2 ----------
    // Pre-stage13 pairs (2j,2j+1), j = 4t+g. Post-stage13: even=Z[kappa], odd=Z[kappa+4096],
    // kappa = 1024*brev2(g) + R, R = brev10(t). Partner pair: thread tp=brev10(1024-R),
    // pair 3-g. t==0: partner = own pair TBL[g]={0(swap),1,3,2}.
    float2 u[4];
    {
        const int R  = brev10(t);
        const int tp = (R == 0) ? 0 : brev10(1024 - R);
        __sincosf((float)M_PI / 4096.f * (float)R, &sn, &cs);
        const float2 wR = make_float2(cs, sn);    // exp(+i*pi*R/4096)
        const float invN = 1.f / 8192.f;
        // W_U(g) = wR * exp(+i*pi*brev2(g)/4) ; brev2(g) = {0,2,1,3}
        const float2 rc[4] = { make_float2(1.f, 0.f),  make_float2(0.f, 1.f),
                               make_float2(RT_H, RT_H), make_float2(-RT_H, RT_H) };
        const int TBL[4] = {0, 1, 3, 2};
        #pragma unroll
        for (int g = 0; g < 4; ++g) {
            int pg = (t == 0) ? TBL[g] : (3 - g);
            float4 q = *(const float4*)&z[SW(8 * t + 2 * g)];
            float4 r = *(const float4*)&z[SW(8 * tp + 2 * pg)];
            float2 A  = make_float2(q.x + q.z, q.y + q.w);
            float2 B  = make_float2(q.x - q.z, q.y - q.w);
            float2 PA = make_float2(r.x + r.z, r.y + r.w);
            float2 PB = make_float2(r.x - r.z, r.y - r.w);
            if (t == 0 && g == 0) { float2 sw = PA; PA = PB; PB = sw; }   // kappa=0 self-pair
            u[g] = mega_combine(A, B, PA, PB, cmul(wR, rc[g]), invN);
        }
        // inverse h=1: W=1 ; h=2: W={1,i}
        bf_dit1(u[0], u[1]);
        bf_dit1(u[2], u[3]);
        bf_dit1(u[0], u[2]);
        bf_diti(u[1], u[3]);
    }
    __syncthreads();              // all pair/partner reads complete before overwrite
    *(float4*)&z[SW(4 * t)]     = make_float4(u[0].x, u[0].y, u[1].x, u[1].y);
    *(float4*)&z[SW(4 * t + 2)] = make_float4(u[2].x, u[2].y, u[3].x, u[3].y);
    __syncthreads();

    // ---------- S2: h=4,8; idx = lo + 4m + 16hi ----------
    {
        const int lo = t & 3, hi = t >> 2;
        #pragma unroll
        for (int m = 0; m < 4; ++m) u[m] = z[SW(lo + 4 * m + 16 * hi)];
        __sincosf((float)M_PI / 8.f * (float)lo, &sn, &cs);
        fft4_dit(u, make_float2(cs, sn));
        #pragma unroll
        for (int m = 0; m < 4; ++m) z[SW(lo + 4 * m + 16 * hi)] = u[m];
    }
    __syncthreads();

    // ---------- S3: h=16,32; idx = lo + 16m + 64hi ----------
    {
        const int lo = t & 15, hi = t >> 4;
        #pragma unroll
        for (int m = 0; m < 4; ++m) u[m] = z[SW(lo + 16 * m + 64 * hi)];
        __sincosf((float)M_PI / 32.f * (float)lo, &sn, &cs);
        fft4_dit(u, make_float2(cs, sn));
        #pragma unroll
        for (int m = 0; m < 4; ++m) z[SW(lo + 16 * m + 64 * hi)] = u[m];
    }
    __syncthreads();

    // ---------- S4: h=64,128; idx = lo + 64m + 256hi ----------
    {
        const int lo = t & 63, hi = t >> 6;
        #pragma unroll
        for (int m = 0; m < 4; ++m) u[m] = z[SW(lo + 64 * m + 256 * hi)];
        __sincosf((float)M_PI / 128.f * (float)lo, &sn, &cs);
        fft4_dit(u, make_float2(cs, sn));
        #pragma unroll
        for (int m = 0; m < 4; ++m) z[SW(lo + 64 * m + 256 * hi)] = u[m];
    }
    __syncthreads();

    // ---------- S5: h=256,512; idx = lo + 256m + 1024hi ----------
    {
        const int lo = t & 255, hi = t >> 8;
        #pragma unroll
        for (int m = 0; m < 4; ++m) u[m] = z[SW(lo + 256 * m + 1024 * hi)];
        __sincosf((float)M_PI / 512.f * (float)lo, &sn, &cs);
        fft4_dit(u, make_float2(cs, sn));
        #pragma unroll
        for (int m = 0; m < 4; ++m) z[SW(lo + 256 * m + 1024 * hi)] = u[m];
    }
    __syncthreads();

    // ---------- S6: h=1024,2048; idx = t + 1024m; LN + L2 from regs ----------
    #pragma unroll
    for (int m = 0; m < 4; ++m) u[m] = z[SW(t + 1024 * m)];
    __sincosf((float)M_PI / 2048.f * (float)t, &sn, &cs);
    fft4_dit(u, make_float2(cs, sn));
    // u[m] = u[t+1024m]: fused[2i] = .x, fused[2i+1] = .y

    float lsum = 0.f, lsq = 0.f;
    #pragma unroll
    for (int m = 0; m < 4; ++m) {
        lsum += u[m].x + u[m].y;
        lsq  += u[m].x * u[m].x + u[m].y * u[m].y;
    }
    #pragma unroll
    for (int k = 32; k >= 1; k >>= 1) { lsum += __shfl_xor(lsum, k); lsq += __shfl_xor(lsq, k); }
    const int wid = t >> 6, lane = t & 63;
    __syncthreads();                       // S6 reads complete before stash reuse
    if (lane == 0) z[wid] = make_float2(lsum, lsq);
    __syncthreads();
    float tsum = 0.f, tsq = 0.f;
    #pragma unroll
    for (int w = 0; w < 16; ++w) { tsum += z[w].x; tsq += z[w].y; }
    const float mu   = tsum * (1.f / (float)DF);
    const float var  = tsq * (1.f / (float)DF) - mu * mu;
    const float rstd = rsqrtf(var + 1e-5f);

    const float2* g2  = (const float2*)gamma;
    const float2* bt2 = (const float2*)beta;
    float lsq2 = 0.f;
    #pragma unroll
    for (int m = 0; m < 4; ++m) {
        int i = t + 1024 * m;
        float2 g = g2[i], bb = bt2[i];
        float ne = (u[m].x - mu) * rstd * g.x + bb.x;
        float no = (u[m].y - mu) * rstd * g.y + bb.y;
        u[m] = make_float2(ne, no);
        lsq2 += ne * ne + no * no;
    }
    #pragma unroll
    for (int k = 32; k >= 1; k >>= 1) lsq2 += __shfl_xor(lsq2, k);
    if (lane == 0) z[32 + wid].x = lsq2;   // slots [32,48): untouched by round-1 reads
    __syncthreads();
    float t2 = 0.f;
    #pragma unroll
    for (int w = 0; w < 16; ++w) t2 += z[32 + w].x;
    const float inv = 1.f / fmaxf(sqrtf(t2), 1e-12f);

    float2* o2 = (float2*)(out + (size_t)row * DF);
    #pragma unroll
    for (int m = 0; m < 4; ++m)
        o2[t + 1024 * m] = make_float2(u[m].x * inv, u[m].y * inv);
}

extern "C" void kernel_launch(void* const* d_in, const int* in_sizes, int n_in,
                              void* d_out, int out_size, void* d_ws, size_t ws_size,
                              hipStream_t stream) {
    const float* x     = (const float*)d_in[0];
    const float* y     = (const float*)d_in[1];
    const float* s1    = (const float*)d_in[2];
    const float* s2    = (const float*)d_in[3];
    const float* gamma = (const float*)d_in[4];
    const float* beta  = (const float*)d_in[5];
    const int*   h1    = (const int*)d_in[6];
    const int*   h2    = (const int*)d_in[7];
    float* out = (float*)d_out;

    hipLaunchKernelGGL(mcb5, dim3(4096), dim3(NT), 0, stream,
                       x, y, s1, s2, gamma, beta, h1, h2, out);
}